// Round 1
// baseline (1213.718 us; speedup 1.0000x reference)
//
#include <hip/hip_runtime.h>

#define NFFT 16384
#define LSIG 8192
#define NH   1024
#define NTH  512
#define LDSN (NFFT + (NFFT >> 5))   // 16896 floats per plane (pad every 32)

__device__ __forceinline__ int PADI(int i) { return i + (i >> 5); }

struct cplx { float x, y; };
__device__ __forceinline__ cplx cadd(cplx a, cplx b){ return {a.x+b.x, a.y+b.y}; }
__device__ __forceinline__ cplx csub(cplx a, cplx b){ return {a.x-b.x, a.y-b.y}; }
__device__ __forceinline__ cplx cmul(cplx a, cplx b){ return {a.x*b.x - a.y*b.y, a.x*b.y + a.y*b.x}; }

// w32[k] = (cos(2*pi*k/32), sin(2*pi*k/32)), k=0..15
constexpr float W32C[16] = {
  1.0f, 0.9807852804f, 0.9238795325f, 0.8314696123f,
  0.7071067812f, 0.5555702330f, 0.3826834324f, 0.1950903220f,
  0.0f, -0.1950903220f, -0.3826834324f, -0.5555702330f,
  -0.7071067812f, -0.8314696123f, -0.9238795325f, -0.9807852804f };
constexpr float W32S[16] = {
  0.0f, 0.1950903220f, 0.3826834324f, 0.5555702330f,
  0.7071067812f, 0.8314696123f, 0.9238795325f, 0.9807852804f,
  1.0f, 0.9807852804f, 0.9238795325f, 0.8314696123f,
  0.7071067812f, 0.5555702330f, 0.3826834324f, 0.1950903220f };
constexpr int BR3[8] = {0,4,2,6,1,5,3,7};

// In-register radix-2 cascade. Forward: natural in -> bit-reversed out (DIF).
// Inverse: bit-reversed in -> natural out (exact layer-by-layer inverse, no 1/N).
template<int N, bool INV>
__device__ __forceinline__ void fft_regs(cplx* z) {
  if (!INV) {
    #pragma unroll
    for (int sp = N/2; sp >= 1; sp >>= 1) {
      #pragma unroll
      for (int b = 0; b < N; b += 2*sp) {
        #pragma unroll
        for (int r = 0; r < sp; ++r) {
          cplx u = z[b+r], v = z[b+r+sp];
          z[b+r] = cadd(u, v);
          cplx d = csub(u, v);
          int kk = r * (16 / sp);       // W_{2sp}^r = W_32^{r*16/sp}
          z[b+r+sp] = cmul(d, cplx{W32C[kk], -W32S[kk]});
        }
      }
    }
  } else {
    #pragma unroll
    for (int sp = 1; sp <= N/2; sp <<= 1) {
      #pragma unroll
      for (int b = 0; b < N; b += 2*sp) {
        #pragma unroll
        for (int r = 0; r < sp; ++r) {
          cplx t0 = z[b+r], t1 = z[b+r+sp];
          int kk = r * (16 / sp);
          cplx w = cmul(t1, cplx{W32C[kk], W32S[kk]});   // conj twiddle
          z[b+r]    = cadd(t0, w);
          z[b+r+sp] = csub(t0, w);
        }
      }
    }
  }
}

// One LDS radix-8 stage of the 16384-pt FFT (sub-problem size M = 8*S).
// Forward: y[base+m*S] = W_M^{r*m} * DFT8_j(x[base+j*S]).
// Inverse: exact inverse of the above (conj twiddle, inverse DFT8, no 1/8).
template<int S, bool INV>
__device__ __forceinline__ void stage8(float* sre, float* sim, int tid) {
  const float ang1 = (INV ? 2.0f : -2.0f) * 3.14159265358979f / (float)(8 * S);
  #pragma unroll
  for (int it = 0; it < (NFFT/8)/NTH; ++it) {   // 4 butterflies per thread
    int bf = tid + it * NTH;                    // 0..2047
    int q = bf / S;
    int r = bf - q * S;
    int base = q * (8 * S) + r;
    float sn, cs;
    __sincosf(ang1 * (float)r, &sn, &cs);
    cplx w1 = {cs, sn};
    cplx wp[8];
    wp[0] = {1.0f, 0.0f};
    #pragma unroll
    for (int m = 1; m < 8; ++m) wp[m] = cmul(wp[m-1], w1);

    cplx a[8];
    if (!INV) {
      #pragma unroll
      for (int j = 0; j < 8; ++j) { int idx = PADI(base + j*S); a[j] = {sre[idx], sim[idx]}; }
      fft_regs<8,false>(a);                     // a[p] = B[BR3[p]]
      #pragma unroll
      for (int p = 0; p < 8; ++p) {
        int m = BR3[p];
        cplx o = cmul(a[p], wp[m]);
        int idx = PADI(base + m*S);
        sre[idx] = o.x; sim[idx] = o.y;
      }
    } else {
      #pragma unroll
      for (int p = 0; p < 8; ++p) {
        int m = BR3[p];
        int idx = PADI(base + m*S);
        cplx v = {sre[idx], sim[idx]};
        a[p] = cmul(v, wp[m]);                  // strip forward twiddle
      }
      fft_regs<8,true>(a);                      // recover natural a[j]
      #pragma unroll
      for (int j = 0; j < 8; ++j) { int idx = PADI(base + j*S); sre[idx] = a[j].x; sim[idx] = a[j].y; }
    }
  }
}

__global__ __launch_bounds__(NTH, 2)
void fftconv_kernel(const float* __restrict__ u, const float* __restrict__ kin,
                    float* __restrict__ out) {
  __shared__ float sre[LDSN];
  __shared__ float sim[LDSN];
  const int tid = threadIdx.x;
  const int bid = blockIdx.x;       // 4096 blocks = 1024 h * 4 batch-pairs
  const int h  = bid >> 2;
  const int pr = bid & 3;

  // ---------------- K row FFT (kept in registers, scaled by 1/NFFT) ----------
  const float* krow = kin + (size_t)h * LSIG;
  #pragma unroll
  for (int c = 0; c < 4; ++c) {
    int i0 = (c * NTH + tid) * 4;
    float4 v = *reinterpret_cast<const float4*>(krow + i0);
    int p0 = PADI(i0);
    sre[p0+0]=v.x; sre[p0+1]=v.y; sre[p0+2]=v.z; sre[p0+3]=v.w;
    sim[p0+0]=0.f; sim[p0+1]=0.f; sim[p0+2]=0.f; sim[p0+3]=0.f;
    int p1 = PADI(i0 + LSIG);
    sre[p1+0]=0.f; sre[p1+1]=0.f; sre[p1+2]=0.f; sre[p1+3]=0.f;
    sim[p1+0]=0.f; sim[p1+1]=0.f; sim[p1+2]=0.f; sim[p1+3]=0.f;
  }
  __syncthreads();
  stage8<2048,false>(sre, sim, tid); __syncthreads();
  stage8< 256,false>(sre, sim, tid); __syncthreads();
  stage8<  32,false>(sre, sim, tid); __syncthreads();

  cplx kreg[32];
  {
    cplx z[32];
    #pragma unroll
    for (int e = 0; e < 32; ++e) { int idx = PADI(tid*32 + e); z[e] = {sre[idx], sim[idx]}; }
    __syncthreads();               // everyone done reading K data before LDS reuse
    fft_regs<32,false>(z);
    const float scl = 1.0f / (float)NFFT;
    #pragma unroll
    for (int e = 0; e < 32; ++e) kreg[e] = {z[e].x * scl, z[e].y * scl};
  }

  // ---------------- U pair: z = u[2p] + i*u[2p+1] ----------------------------
  const float* u0 = u + ((size_t)(2*pr) * NH + h) * LSIG;
  const float* u1 = u0 + (size_t)NH * LSIG;
  #pragma unroll
  for (int c = 0; c < 4; ++c) {
    int i0 = (c * NTH + tid) * 4;
    float4 a = *reinterpret_cast<const float4*>(u0 + i0);
    float4 b = *reinterpret_cast<const float4*>(u1 + i0);
    int p0 = PADI(i0);
    sre[p0+0]=a.x; sre[p0+1]=a.y; sre[p0+2]=a.z; sre[p0+3]=a.w;
    sim[p0+0]=b.x; sim[p0+1]=b.y; sim[p0+2]=b.z; sim[p0+3]=b.w;
    int p1 = PADI(i0 + LSIG);
    sre[p1+0]=0.f; sre[p1+1]=0.f; sre[p1+2]=0.f; sre[p1+3]=0.f;
    sim[p1+0]=0.f; sim[p1+1]=0.f; sim[p1+2]=0.f; sim[p1+3]=0.f;
  }
  __syncthreads();
  stage8<2048,false>(sre, sim, tid); __syncthreads();
  stage8< 256,false>(sre, sim, tid); __syncthreads();
  stage8<  32,false>(sre, sim, tid); __syncthreads();

  // ---- fused: local 32-pt FFT, pointwise multiply, local 32-pt inverse ------
  {
    cplx z[32];
    #pragma unroll
    for (int e = 0; e < 32; ++e) { int idx = PADI(tid*32 + e); z[e] = {sre[idx], sim[idx]}; }
    fft_regs<32,false>(z);
    #pragma unroll
    for (int e = 0; e < 32; ++e) z[e] = cmul(z[e], kreg[e]);   // same scrambled order
    fft_regs<32,true>(z);
    #pragma unroll
    for (int e = 0; e < 32; ++e) { int idx = PADI(tid*32 + e); sre[idx] = z[e].x; sim[idx] = z[e].y; }
  }
  __syncthreads();
  stage8<  32,true>(sre, sim, tid); __syncthreads();
  stage8< 256,true>(sre, sim, tid); __syncthreads();
  stage8<2048,true>(sre, sim, tid); __syncthreads();

  // ---------------- write first 8192 samples: y0 = Re, y1 = Im ---------------
  float* o0 = out + ((size_t)(2*pr) * NH + h) * LSIG;
  float* o1 = o0 + (size_t)NH * LSIG;
  #pragma unroll
  for (int c = 0; c < 4; ++c) {
    int i0 = (c * NTH + tid) * 4;
    int p0 = PADI(i0);
    float4 a = {sre[p0], sre[p0+1], sre[p0+2], sre[p0+3]};
    float4 b = {sim[p0], sim[p0+1], sim[p0+2], sim[p0+3]};
    *reinterpret_cast<float4*>(o0 + i0) = a;
    *reinterpret_cast<float4*>(o1 + i0) = b;
  }
}

extern "C" void kernel_launch(void* const* d_in, const int* in_sizes, int n_in,
                              void* d_out, int out_size, void* d_ws, size_t ws_size,
                              hipStream_t stream) {
  (void)in_sizes; (void)n_in; (void)d_ws; (void)ws_size; (void)out_size;
  const float* u = (const float*)d_in[0];
  const float* k = (const float*)d_in[1];
  float* out = (float*)d_out;
  dim3 grid(4096), block(NTH);
  hipLaunchKernelGGL(fftconv_kernel, grid, block, 0, stream, u, k, out);
}

// Round 2
// 1114.586 us; speedup vs baseline: 1.0889x; 1.0889x over previous
//
#include <hip/hip_runtime.h>

#define NFFT 16384
#define LSIG 8192
#define NH   1024
#define NTH  512
#define LDSN (NFFT + (NFFT >> 5))   // 16896 floats per plane (pad every 32)

__device__ __forceinline__ int PADI(int i) { return i + (i >> 5); }

struct cplx { float x, y; };
__device__ __forceinline__ cplx cadd(cplx a, cplx b){ return {a.x+b.x, a.y+b.y}; }
__device__ __forceinline__ cplx csub(cplx a, cplx b){ return {a.x-b.x, a.y-b.y}; }
__device__ __forceinline__ cplx cmul(cplx a, cplx b){ return {a.x*b.x - a.y*b.y, a.x*b.y + a.y*b.x}; }

// w32[k] = (cos(2*pi*k/32), sin(2*pi*k/32)), k=0..15
constexpr float W32C[16] = {
  1.0f, 0.9807852804f, 0.9238795325f, 0.8314696123f,
  0.7071067812f, 0.5555702330f, 0.3826834324f, 0.1950903220f,
  0.0f, -0.1950903220f, -0.3826834324f, -0.5555702330f,
  -0.7071067812f, -0.8314696123f, -0.9238795325f, -0.9807852804f };
constexpr float W32S[16] = {
  0.0f, 0.1950903220f, 0.3826834324f, 0.5555702330f,
  0.7071067812f, 0.8314696123f, 0.9238795325f, 0.9807852804f,
  1.0f, 0.9807852804f, 0.9238795325f, 0.8314696123f,
  0.7071067812f, 0.5555702330f, 0.3826834324f, 0.1950903220f };
constexpr int BR3[8] = {0,4,2,6,1,5,3,7};

// One radix-2 pass with COMPILE-TIME span SP. All z[] indices are constants
// after unrolling -> arrays stay in registers (rule #20: no runtime indexing).
template<int N, int SP, bool INV>
__device__ __forceinline__ void fft_pass(cplx* z) {
  #pragma unroll
  for (int b = 0; b < N; b += 2*SP) {
    #pragma unroll
    for (int r = 0; r < SP; ++r) {
      const int kk = r * (16 / SP);        // W_{2SP}^r = W32^{r*16/SP}, SP<=16
      if (!INV) {
        cplx u = z[b+r], v = z[b+r+SP];
        z[b+r] = cadd(u, v);
        cplx d = csub(u, v);
        z[b+r+SP] = cmul(d, cplx{W32C[kk], -W32S[kk]});
      } else {
        cplx t0 = z[b+r], t1 = z[b+r+SP];
        cplx w = cmul(t1, cplx{W32C[kk], W32S[kk]});   // conj twiddle
        z[b+r]    = cadd(t0, w);
        z[b+r+SP] = csub(t0, w);
      }
    }
  }
}

// Forward: natural in -> bit-reversed out (DIF). Inverse: exact mirror, no 1/N.
template<int N, bool INV>
__device__ __forceinline__ void fft_regs(cplx* z) {
  if constexpr (!INV) {
    if constexpr (N >= 32) fft_pass<N,16,false>(z);
    if constexpr (N >= 16) fft_pass<N, 8,false>(z);
    if constexpr (N >=  8) fft_pass<N, 4,false>(z);
    if constexpr (N >=  4) fft_pass<N, 2,false>(z);
    fft_pass<N,1,false>(z);
  } else {
    fft_pass<N,1,true>(z);
    if constexpr (N >=  4) fft_pass<N, 2,true>(z);
    if constexpr (N >=  8) fft_pass<N, 4,true>(z);
    if constexpr (N >= 16) fft_pass<N, 8,true>(z);
    if constexpr (N >= 32) fft_pass<N,16,true>(z);
  }
}

// One LDS radix-8 stage of the 16384-pt FFT (sub-problem size M = 8*S).
template<int S, bool INV>
__device__ __forceinline__ void stage8(float* sre, float* sim, int tid) {
  const float ang1 = (INV ? 2.0f : -2.0f) * 3.14159265358979f / (float)(8 * S);
  #pragma unroll
  for (int it = 0; it < (NFFT/8)/NTH; ++it) {   // 4 butterflies per thread
    int bf = tid + it * NTH;                    // 0..2047
    int q = bf / S;
    int r = bf - q * S;
    int base = q * (8 * S) + r;
    float sn, cs;
    __sincosf(ang1 * (float)r, &sn, &cs);
    cplx w1 = {cs, sn};
    cplx wp[8];
    wp[0] = {1.0f, 0.0f};
    #pragma unroll
    for (int m = 1; m < 8; ++m) wp[m] = cmul(wp[m-1], w1);

    cplx a[8];
    if (!INV) {
      #pragma unroll
      for (int j = 0; j < 8; ++j) { int idx = PADI(base + j*S); a[j] = {sre[idx], sim[idx]}; }
      fft_regs<8,false>(a);                     // a[p] = B[BR3[p]]
      #pragma unroll
      for (int p = 0; p < 8; ++p) {
        const int m = BR3[p];
        cplx o = cmul(a[p], wp[m]);
        int idx = PADI(base + m*S);
        sre[idx] = o.x; sim[idx] = o.y;
      }
    } else {
      #pragma unroll
      for (int p = 0; p < 8; ++p) {
        const int m = BR3[p];
        int idx = PADI(base + m*S);
        cplx v = {sre[idx], sim[idx]};
        a[p] = cmul(v, wp[m]);                  // strip forward twiddle
      }
      fft_regs<8,true>(a);                      // recover natural a[j]
      #pragma unroll
      for (int j = 0; j < 8; ++j) { int idx = PADI(base + j*S); sre[idx] = a[j].x; sim[idx] = a[j].y; }
    }
  }
}

__global__ __launch_bounds__(NTH, 2)
void fftconv_kernel(const float* __restrict__ u, const float* __restrict__ kin,
                    float* __restrict__ out) {
  __shared__ float sre[LDSN];
  __shared__ float sim[LDSN];
  const int tid = threadIdx.x;
  const int bid = blockIdx.x;       // 4096 blocks = 1024 h * 4 batch-pairs
  const int h  = bid >> 2;
  const int pr = bid & 3;

  // ---------------- K row FFT (kept in registers, scaled by 1/NFFT) ----------
  const float* krow = kin + (size_t)h * LSIG;
  #pragma unroll
  for (int c = 0; c < 4; ++c) {
    int i0 = (c * NTH + tid) * 4;
    float4 v = *reinterpret_cast<const float4*>(krow + i0);
    int p0 = PADI(i0);
    sre[p0+0]=v.x; sre[p0+1]=v.y; sre[p0+2]=v.z; sre[p0+3]=v.w;
    sim[p0+0]=0.f; sim[p0+1]=0.f; sim[p0+2]=0.f; sim[p0+3]=0.f;
    int p1 = PADI(i0 + LSIG);
    sre[p1+0]=0.f; sre[p1+1]=0.f; sre[p1+2]=0.f; sre[p1+3]=0.f;
    sim[p1+0]=0.f; sim[p1+1]=0.f; sim[p1+2]=0.f; sim[p1+3]=0.f;
  }
  __syncthreads();
  stage8<2048,false>(sre, sim, tid); __syncthreads();
  stage8< 256,false>(sre, sim, tid); __syncthreads();
  stage8<  32,false>(sre, sim, tid); __syncthreads();

  cplx kreg[32];
  {
    cplx z[32];
    #pragma unroll
    for (int e = 0; e < 32; ++e) { int idx = PADI(tid*32 + e); z[e] = {sre[idx], sim[idx]}; }
    __syncthreads();               // everyone done reading K data before LDS reuse
    fft_regs<32,false>(z);
    const float scl = 1.0f / (float)NFFT;
    #pragma unroll
    for (int e = 0; e < 32; ++e) kreg[e] = {z[e].x * scl, z[e].y * scl};
  }

  // ---------------- U pair: z = u[2p] + i*u[2p+1] ----------------------------
  const float* u0 = u + ((size_t)(2*pr) * NH + h) * LSIG;
  const float* u1 = u0 + (size_t)NH * LSIG;
  #pragma unroll
  for (int c = 0; c < 4; ++c) {
    int i0 = (c * NTH + tid) * 4;
    float4 a = *reinterpret_cast<const float4*>(u0 + i0);
    float4 b = *reinterpret_cast<const float4*>(u1 + i0);
    int p0 = PADI(i0);
    sre[p0+0]=a.x; sre[p0+1]=a.y; sre[p0+2]=a.z; sre[p0+3]=a.w;
    sim[p0+0]=b.x; sim[p0+1]=b.y; sim[p0+2]=b.z; sim[p0+3]=b.w;
    int p1 = PADI(i0 + LSIG);
    sre[p1+0]=0.f; sre[p1+1]=0.f; sre[p1+2]=0.f; sre[p1+3]=0.f;
    sim[p1+0]=0.f; sim[p1+1]=0.f; sim[p1+2]=0.f; sim[p1+3]=0.f;
  }
  __syncthreads();
  stage8<2048,false>(sre, sim, tid); __syncthreads();
  stage8< 256,false>(sre, sim, tid); __syncthreads();
  stage8<  32,false>(sre, sim, tid); __syncthreads();

  // ---- fused: local 32-pt FFT, pointwise multiply, local 32-pt inverse ------
  {
    cplx z[32];
    #pragma unroll
    for (int e = 0; e < 32; ++e) { int idx = PADI(tid*32 + e); z[e] = {sre[idx], sim[idx]}; }
    fft_regs<32,false>(z);
    #pragma unroll
    for (int e = 0; e < 32; ++e) z[e] = cmul(z[e], kreg[e]);   // same scrambled order
    fft_regs<32,true>(z);
    #pragma unroll
    for (int e = 0; e < 32; ++e) { int idx = PADI(tid*32 + e); sre[idx] = z[e].x; sim[idx] = z[e].y; }
  }
  __syncthreads();
  stage8<  32,true>(sre, sim, tid); __syncthreads();
  stage8< 256,true>(sre, sim, tid); __syncthreads();
  stage8<2048,true>(sre, sim, tid); __syncthreads();

  // ---------------- write first 8192 samples: y0 = Re, y1 = Im ---------------
  float* o0 = out + ((size_t)(2*pr) * NH + h) * LSIG;
  float* o1 = o0 + (size_t)NH * LSIG;
  #pragma unroll
  for (int c = 0; c < 4; ++c) {
    int i0 = (c * NTH + tid) * 4;
    int p0 = PADI(i0);
    float4 a = {sre[p0], sre[p0+1], sre[p0+2], sre[p0+3]};
    float4 b = {sim[p0], sim[p0+1], sim[p0+2], sim[p0+3]};
    *reinterpret_cast<float4*>(o0 + i0) = a;
    *reinterpret_cast<float4*>(o1 + i0) = b;
  }
}

extern "C" void kernel_launch(void* const* d_in, const int* in_sizes, int n_in,
                              void* d_out, int out_size, void* d_ws, size_t ws_size,
                              hipStream_t stream) {
  (void)in_sizes; (void)n_in; (void)d_ws; (void)ws_size; (void)out_size;
  const float* u = (const float*)d_in[0];
  const float* k = (const float*)d_in[1];
  float* out = (float*)d_out;
  dim3 grid(4096), block(NTH);
  hipLaunchKernelGGL(fftconv_kernel, grid, block, 0, stream, u, k, out);
}

// Round 3
// 1114.426 us; speedup vs baseline: 1.0891x; 1.0001x over previous
//
#include <hip/hip_runtime.h>

#define NFFT 16384
#define LSIG 8192
#define NH   1024
#define NTH  512
#define LDSN (NFFT + (NFFT >> 5))   // 16896 floats per plane (pad every 32)

__device__ __forceinline__ int PADI(int i) { return i + (i >> 5); }

struct cplx { float x, y; };
__device__ __forceinline__ cplx cadd(cplx a, cplx b){ return {a.x+b.x, a.y+b.y}; }
__device__ __forceinline__ cplx csub(cplx a, cplx b){ return {a.x-b.x, a.y-b.y}; }
__device__ __forceinline__ cplx cmul(cplx a, cplx b){ return {a.x*b.x - a.y*b.y, a.x*b.y + a.y*b.x}; }

// w32[k] = (cos(2*pi*k/32), sin(2*pi*k/32)), k=0..15
constexpr float W32C[16] = {
  1.0f, 0.9807852804f, 0.9238795325f, 0.8314696123f,
  0.7071067812f, 0.5555702330f, 0.3826834324f, 0.1950903220f,
  0.0f, -0.1950903220f, -0.3826834324f, -0.5555702330f,
  -0.7071067812f, -0.8314696123f, -0.9238795325f, -0.9807852804f };
constexpr float W32S[16] = {
  0.0f, 0.1950903220f, 0.3826834324f, 0.5555702330f,
  0.7071067812f, 0.8314696123f, 0.9238795325f, 0.9807852804f,
  1.0f, 0.9807852804f, 0.9238795325f, 0.8314696123f,
  0.7071067812f, 0.5555702330f, 0.3826834324f, 0.1950903220f };
constexpr int BR3[8] = {0,4,2,6,1,5,3,7};

// One radix-2 pass with COMPILE-TIME span SP. All z[] indices are constants
// after unrolling -> arrays stay in registers (rule #20: no runtime indexing).
template<int N, int SP, bool INV>
__device__ __forceinline__ void fft_pass(cplx* z) {
  #pragma unroll
  for (int b = 0; b < N; b += 2*SP) {
    #pragma unroll
    for (int r = 0; r < SP; ++r) {
      const int kk = r * (16 / SP);        // W_{2SP}^r = W32^{r*16/SP}, SP<=16
      if (!INV) {
        cplx u = z[b+r], v = z[b+r+SP];
        z[b+r] = cadd(u, v);
        cplx d = csub(u, v);
        z[b+r+SP] = cmul(d, cplx{W32C[kk], -W32S[kk]});
      } else {
        cplx t0 = z[b+r], t1 = z[b+r+SP];
        cplx w = cmul(t1, cplx{W32C[kk], W32S[kk]});   // conj twiddle
        z[b+r]    = cadd(t0, w);
        z[b+r+SP] = csub(t0, w);
      }
    }
  }
}

// Forward: natural in -> bit-reversed out (DIF). Inverse: exact mirror, no 1/N.
template<int N, bool INV>
__device__ __forceinline__ void fft_regs(cplx* z) {
  if constexpr (!INV) {
    if constexpr (N >= 32) fft_pass<N,16,false>(z);
    if constexpr (N >= 16) fft_pass<N, 8,false>(z);
    if constexpr (N >=  8) fft_pass<N, 4,false>(z);
    if constexpr (N >=  4) fft_pass<N, 2,false>(z);
    fft_pass<N,1,false>(z);
  } else {
    fft_pass<N,1,true>(z);
    if constexpr (N >=  4) fft_pass<N, 2,true>(z);
    if constexpr (N >=  8) fft_pass<N, 4,true>(z);
    if constexpr (N >= 16) fft_pass<N, 8,true>(z);
    if constexpr (N >= 32) fft_pass<N,16,true>(z);
  }
}

// One LDS radix-8 stage of the 16384-pt FFT (sub-problem size M = 8*S).
template<int S, bool INV>
__device__ __forceinline__ void stage8(float* sre, float* sim, int tid) {
  const float ang1 = (INV ? 2.0f : -2.0f) * 3.14159265358979f / (float)(8 * S);
  #pragma unroll
  for (int it = 0; it < (NFFT/8)/NTH; ++it) {   // 4 butterflies per thread
    int bf = tid + it * NTH;                    // 0..2047
    int q = bf / S;
    int r = bf - q * S;
    int base = q * (8 * S) + r;
    float sn, cs;
    __sincosf(ang1 * (float)r, &sn, &cs);
    cplx w1 = {cs, sn};
    cplx wp[8];
    wp[0] = {1.0f, 0.0f};
    #pragma unroll
    for (int m = 1; m < 8; ++m) wp[m] = cmul(wp[m-1], w1);

    cplx a[8];
    if (!INV) {
      #pragma unroll
      for (int j = 0; j < 8; ++j) { int idx = PADI(base + j*S); a[j] = {sre[idx], sim[idx]}; }
      fft_regs<8,false>(a);                     // a[p] = B[BR3[p]]
      #pragma unroll
      for (int p = 0; p < 8; ++p) {
        const int m = BR3[p];
        cplx o = cmul(a[p], wp[m]);
        int idx = PADI(base + m*S);
        sre[idx] = o.x; sim[idx] = o.y;
      }
    } else {
      #pragma unroll
      for (int p = 0; p < 8; ++p) {
        const int m = BR3[p];
        int idx = PADI(base + m*S);
        cplx v = {sre[idx], sim[idx]};
        a[p] = cmul(v, wp[m]);                  // strip forward twiddle
      }
      fft_regs<8,true>(a);                      // recover natural a[j]
      #pragma unroll
      for (int j = 0; j < 8; ++j) { int idx = PADI(base + j*S); sre[idx] = a[j].x; sim[idx] = a[j].y; }
    }
  }
}

// launch_bounds(512, 1): LDS (132 KiB) already caps at 1 block/CU = 2 waves/SIMD,
// so allow the 256-VGPR budget. (512,2) was interpreted as 2 blocks/CU -> 128-VGPR
// cap -> ~5 GB of spill traffic (round-2 counters).
__global__ __launch_bounds__(NTH, 1)
void fftconv_kernel(const float* __restrict__ u, const float* __restrict__ kin,
                    float* __restrict__ out) {
  __shared__ float sre[LDSN];
  __shared__ float sim[LDSN];
  const int tid = threadIdx.x;
  const int bid = blockIdx.x;       // 4096 blocks = 1024 h * 4 batch-pairs
  const int h  = bid >> 2;
  const int pr = bid & 3;

  // ---------------- K row FFT (kept in registers, scaled by 1/NFFT) ----------
  const float* krow = kin + (size_t)h * LSIG;
  #pragma unroll
  for (int c = 0; c < 4; ++c) {
    int i0 = (c * NTH + tid) * 4;
    float4 v = *reinterpret_cast<const float4*>(krow + i0);
    int p0 = PADI(i0);
    sre[p0+0]=v.x; sre[p0+1]=v.y; sre[p0+2]=v.z; sre[p0+3]=v.w;
    sim[p0+0]=0.f; sim[p0+1]=0.f; sim[p0+2]=0.f; sim[p0+3]=0.f;
    int p1 = PADI(i0 + LSIG);
    sre[p1+0]=0.f; sre[p1+1]=0.f; sre[p1+2]=0.f; sre[p1+3]=0.f;
    sim[p1+0]=0.f; sim[p1+1]=0.f; sim[p1+2]=0.f; sim[p1+3]=0.f;
  }
  __syncthreads();
  stage8<2048,false>(sre, sim, tid); __syncthreads();
  stage8< 256,false>(sre, sim, tid); __syncthreads();
  stage8<  32,false>(sre, sim, tid); __syncthreads();

  cplx kreg[32];
  {
    cplx z[32];
    #pragma unroll
    for (int e = 0; e < 32; ++e) { int idx = PADI(tid*32 + e); z[e] = {sre[idx], sim[idx]}; }
    __syncthreads();               // everyone done reading K data before LDS reuse
    fft_regs<32,false>(z);
    const float scl = 1.0f / (float)NFFT;
    #pragma unroll
    for (int e = 0; e < 32; ++e) kreg[e] = {z[e].x * scl, z[e].y * scl};
  }

  // ---------------- U pair: z = u[2p] + i*u[2p+1] ----------------------------
  const float* u0 = u + ((size_t)(2*pr) * NH + h) * LSIG;
  const float* u1 = u0 + (size_t)NH * LSIG;
  #pragma unroll
  for (int c = 0; c < 4; ++c) {
    int i0 = (c * NTH + tid) * 4;
    float4 a = *reinterpret_cast<const float4*>(u0 + i0);
    float4 b = *reinterpret_cast<const float4*>(u1 + i0);
    int p0 = PADI(i0);
    sre[p0+0]=a.x; sre[p0+1]=a.y; sre[p0+2]=a.z; sre[p0+3]=a.w;
    sim[p0+0]=b.x; sim[p0+1]=b.y; sim[p0+2]=b.z; sim[p0+3]=b.w;
    int p1 = PADI(i0 + LSIG);
    sre[p1+0]=0.f; sre[p1+1]=0.f; sre[p1+2]=0.f; sre[p1+3]=0.f;
    sim[p1+0]=0.f; sim[p1+1]=0.f; sim[p1+2]=0.f; sim[p1+3]=0.f;
  }
  __syncthreads();
  stage8<2048,false>(sre, sim, tid); __syncthreads();
  stage8< 256,false>(sre, sim, tid); __syncthreads();
  stage8<  32,false>(sre, sim, tid); __syncthreads();

  // ---- fused: local 32-pt FFT, pointwise multiply, local 32-pt inverse ------
  {
    cplx z[32];
    #pragma unroll
    for (int e = 0; e < 32; ++e) { int idx = PADI(tid*32 + e); z[e] = {sre[idx], sim[idx]}; }
    fft_regs<32,false>(z);
    #pragma unroll
    for (int e = 0; e < 32; ++e) z[e] = cmul(z[e], kreg[e]);   // same scrambled order
    fft_regs<32,true>(z);
    #pragma unroll
    for (int e = 0; e < 32; ++e) { int idx = PADI(tid*32 + e); sre[idx] = z[e].x; sim[idx] = z[e].y; }
  }
  __syncthreads();
  stage8<  32,true>(sre, sim, tid); __syncthreads();
  stage8< 256,true>(sre, sim, tid); __syncthreads();
  stage8<2048,true>(sre, sim, tid); __syncthreads();

  // ---------------- write first 8192 samples: y0 = Re, y1 = Im ---------------
  float* o0 = out + ((size_t)(2*pr) * NH + h) * LSIG;
  float* o1 = o0 + (size_t)NH * LSIG;
  #pragma unroll
  for (int c = 0; c < 4; ++c) {
    int i0 = (c * NTH + tid) * 4;
    int p0 = PADI(i0);
    float4 a = {sre[p0], sre[p0+1], sre[p0+2], sre[p0+3]};
    float4 b = {sim[p0], sim[p0+1], sim[p0+2], sim[p0+3]};
    *reinterpret_cast<float4*>(o0 + i0) = a;
    *reinterpret_cast<float4*>(o1 + i0) = b;
  }
}

extern "C" void kernel_launch(void* const* d_in, const int* in_sizes, int n_in,
                              void* d_out, int out_size, void* d_ws, size_t ws_size,
                              hipStream_t stream) {
  (void)in_sizes; (void)n_in; (void)d_ws; (void)ws_size; (void)out_size;
  const float* u = (const float*)d_in[0];
  const float* k = (const float*)d_in[1];
  float* out = (float*)d_out;
  dim3 grid(4096), block(NTH);
  hipLaunchKernelGGL(fftconv_kernel, grid, block, 0, stream, u, k, out);
}